// Round 9
// baseline (651.949 us; speedup 1.0000x reference)
//
#include <hip/hip_runtime.h>

// ---------------------------------------------------------------------------
// 2-layer GCN + global mean pool, MI355X (gfx950).
//   A_hat = D^{-1/2}(A+I)D^{-1/2}
//   G' = dinv*(X @ W1) fp16 [MFMA fp16];  H'' = dinv*relu(dinv*A_sum(G')+b1)
//   out = pool(dinv*A_sum(H'')) @ W2 + b2
// R19 = R14 structure (best, 196us) with two bounded changes:
//   (1) MFMA operand swap: mfma(A=WB, B=Xfrag) — same fragment data serves
//       both roles (16-dim on lane&15 for A and B) -> lane owns node-row
//       mbase+(lane&15), regs = 4 consecutive cols. C-write: 8 x 8B stores
//       (was 32 x 2B sub-word). Zero repack, identical math.
//   (2) Dispatch diet: final_gemm fused into agg2_pool via last-block ticket
//       (all 2048 blocks tick; empty blocks too); bucket scan ticket-fused
//       into bucket_deg (R17-verified). memset + 5 dispatches (was +6).
//   Aggs: R14 code exactly (8-deep bursts, cvt+add; pads hit L1-hot zero
//   sentinel row -> pad traffic is free, R18 lesson).
//   CSR build: two-level counting sort, zero per-edge global atomics.
// ws_size is 256 MiB; we use ~35 MB.
// ---------------------------------------------------------------------------

#define D 128
#define NGRAPH 64
#define AGG_BLOCKS 2048   // 8192 waves = 32/CU
#define BUCK_SH 9         // bucket = dst >> 9 (width 512)
#define BUCK_W  512
#define MAXBUCK 128       // N <= 65536

typedef _Float16 h16x2 __attribute__((ext_vector_type(2)));
typedef _Float16 f16x8 __attribute__((ext_vector_type(8)));
typedef float    f32x4 __attribute__((ext_vector_type(4)));
typedef unsigned short u16x8 __attribute__((ext_vector_type(8)));

__device__ __forceinline__ float2 h2f(unsigned u) {
    h16x2 h = __builtin_bit_cast(h16x2, u);
    return make_float2((float)h.x, (float)h.y);
}
__device__ __forceinline__ unsigned f2h(float x, float y) {
    h16x2 h;
    h.x = (_Float16)x;
    h.y = (_Float16)y;
    return __builtin_bit_cast(unsigned, h);
}

// --- diagnostic: all-zero output (ws too small) ----------------------------
__global__ void zero_out_kernel(float* __restrict__ out, int n) {
    int i = blockIdx.x * blockDim.x + threadIdx.x;
    if (i < n) out[i] = 0.f;
}

// --- K1: W1 pack (blocks 0..7) | zero sentinel rows (block 8) | bucket
//     scatter (blocks 9..): LDS histogram + per-block span reservation. -----
__global__ __launch_bounds__(256) void pack_scatter_kernel(const float* __restrict__ W1,
                                                           _Float16* __restrict__ WB,
                                                           const int* __restrict__ ei,
                                                           int* __restrict__ bcnt,
                                                           unsigned* __restrict__ buck,
                                                           unsigned* __restrict__ Gz,
                                                           unsigned* __restrict__ Hz,
                                                           int N, int E, int CAP) {
    int b = (int)blockIdx.x;
    int t = (int)threadIdx.x;
    if (b < 8) {
        // WB[((kt*8+nt)*64+lane)*8+j] = W1[(kt*32+(lane>>4)*8+j)*D + nt*16+(lane&15)]
        int idx = b * 256 + t;                         // 0..2047
        int lane = idx & 63;
        int nt   = (idx >> 6) & 7;
        int kt   = idx >> 9;
        int col  = nt * 16 + (lane & 15);
        int krow = kt * 32 + (lane >> 4) * 8;
#pragma unroll
        for (int j = 0; j < 8; ++j)
            WB[idx * 8 + j] = (_Float16)W1[(krow + j) * D + col];
        return;
    }
    if (b == 8) {
        if (t < 64)       Gz[(size_t)N * 64 + t] = 0u;          // Gh row N = 0
        else if (t < 128) Hz[(size_t)N * 64 + (t - 64)] = 0u;   // Hh row N = 0
        return;
    }
    __shared__ unsigned histL[MAXBUCK];
    __shared__ int      baseL[MAXBUCK];
    if (t < MAXBUCK) histL[t] = 0u;
    __syncthreads();

    int e0 = (b - 9) * 1024;
    int bid[4];
    unsigned lidx[4], pk[4];
#pragma unroll
    for (int j = 0; j < 4; ++j) {
        int e = e0 + t + j * 256;
        bid[j] = -1;
        if (e < E) {
            int s = ei[e];
            int d = ei[E + e];
            if (d >= 0 && d < N) {
                s = min(max(s, 0), N - 1);
                bid[j] = d >> BUCK_SH;
                pk[j]  = ((unsigned)d << 16) | (unsigned)s;
            }
        }
    }
#pragma unroll
    for (int j = 0; j < 4; ++j)
        if (bid[j] >= 0) lidx[j] = atomicAdd(&histL[bid[j]], 1u);
    __syncthreads();
    if (t < MAXBUCK && histL[t] > 0u)
        baseL[t] = atomicAdd(&bcnt[t], (int)histL[t]);
    __syncthreads();
#pragma unroll
    for (int j = 0; j < 4; ++j)
        if (bid[j] >= 0) {
            int slot = baseL[bid[j]] + (int)lidx[j];
            if (slot < CAP) buck[(size_t)bid[j] * CAP + slot] = pk[j];
        }
}

// --- K2: per-bucket degree count (LDS atomics) -> deg, dinv, padsum;
//     LAST block (ticket) also scans padsums -> bbase, rowstart[N]. ---------
__global__ __launch_bounds__(256) void bucket_deg_kernel(const unsigned* __restrict__ buck,
                                                         const int* __restrict__ bcnt,
                                                         int* __restrict__ deg,
                                                         float* __restrict__ dinv,
                                                         int* __restrict__ padsum,
                                                         int* __restrict__ bbase,
                                                         int* __restrict__ rowstart,
                                                         int* __restrict__ ticket,
                                                         int N, int CAP, int nbuck) {
    __shared__ int degL[BUCK_W];
    __shared__ int red[256];
    __shared__ int lastFlag;
    int b = (int)blockIdx.x;
    int t = (int)threadIdx.x;
    for (int k = t; k < BUCK_W; k += 256) degL[k] = 0;
    __syncthreads();
    int cnt = min(bcnt[b], CAP);
    const unsigned* bp = buck + (size_t)b * CAP;
    for (int i = t; i < cnt; i += 256)
        atomicAdd(&degL[(bp[i] >> 16) & (BUCK_W - 1)], 1);
    __syncthreads();
    int base = b << BUCK_SH;
    int local = 0;
    for (int k = t; k < BUCK_W; k += 256) {
        int d = base + k;
        if (d < N) {
            int dg = degL[k];
            deg[d]  = dg;
            dinv[d] = rsqrtf((float)dg + 1.0f);
            local  += (dg + 7) & ~7;
        }
    }
    red[t] = local;
    __syncthreads();
    for (int off = 128; off > 0; off >>= 1) {
        if (t < off) red[t] += red[t + off];
        __syncthreads();
    }
    if (t == 0) padsum[b] = red[0];
    __threadfence();
    if (t == 0) lastFlag = (atomicAdd(ticket, 1) == nbuck - 1) ? 1 : 0;
    __syncthreads();
    if (lastFlag) {
        __threadfence();                     // acquire all padsum writes
        __shared__ int s[128];
        int own = (t < nbuck) ? padsum[t] : 0;
        if (t < 128) s[t] = own;
        __syncthreads();
        for (int off = 1; off < 128; off <<= 1) {
            int v = (t < 128 && t >= off) ? s[t - off] : 0;
            __syncthreads();
            if (t < 128) s[t] += v;
            __syncthreads();
        }
        if (t < nbuck) bbase[t] = s[t] - own;        // exclusive
        if (t == 127) rowstart[N] = s[127];
    }
}

// --- K3: fused MFMA GEMM (blocks [0,gb)) + bucket CSR fill ([gb,gb+nbuck)) -
// GEMM: operand-swapped mfma -> lane owns node-row, 8 x 8B C-stores.
// Fill: per-bucket LDS scan of padded degrees -> rowstart; sentinel pads;
// colidx placement via LDS cursors. Zero global atomics.
__global__ __launch_bounds__(256) void gemm_fill_kernel(const float* __restrict__ X,
                                                        const _Float16* __restrict__ WB,
                                                        const float* __restrict__ dinv,
                                                        _Float16* __restrict__ Gh,
                                                        const unsigned* __restrict__ buck,
                                                        const int* __restrict__ bcnt,
                                                        const int* __restrict__ deg,
                                                        const int* __restrict__ bbase,
                                                        int* __restrict__ rowstart,
                                                        unsigned short* __restrict__ colidx,
                                                        int N, int CAP, int gb) {
    if ((int)blockIdx.x >= gb) {
        __shared__ int degS[BUCK_W];    // deg, later absolute cursors
        __shared__ int loff[BUCK_W];
        __shared__ int sc[256];
        int b = (int)blockIdx.x - gb;
        int t = (int)threadIdx.x;
        int base_d = b << BUCK_SH;
        for (int k = t; k < BUCK_W; k += 256) {
            int d = base_d + k;
            degS[k] = (d < N) ? deg[d] : 0;
        }
        __syncthreads();
        // scan pad8 over 512 entries: thread t owns 2t, 2t+1
        int p0 = (degS[2 * t] + 7) & ~7;
        int p1 = (degS[2 * t + 1] + 7) & ~7;
        int own = p0 + p1;
        sc[t] = own;
        __syncthreads();
        for (int off = 1; off < 256; off <<= 1) {
            int v = (t >= off) ? sc[t - off] : 0;
            __syncthreads();
            sc[t] += v;
            __syncthreads();
        }
        int excl = sc[t] - own;
        loff[2 * t]     = excl;
        loff[2 * t + 1] = excl + p0;
        __syncthreads();
        int bb = bbase[b];
        // rowstart + sentinel pads (uses degS as degrees still)
        for (int k = t; k < BUCK_W; k += 256) {
            int d = base_d + k;
            if (d < N) {
                int rs = bb + loff[k];
                rowstart[d] = rs;
                int dg = degS[k];
                int p8 = (dg + 7) & ~7;
                for (int j = dg; j < p8; ++j)
                    colidx[rs + j] = (unsigned short)N;   // sentinel -> zero row
            }
        }
        __syncthreads();
        // convert degS -> absolute cursors
        for (int k = t; k < BUCK_W; k += 256) degS[k] = bb + loff[k];
        __syncthreads();
        int cnt = min(bcnt[b], CAP);
        const unsigned* bp = buck + (size_t)b * CAP;
        for (int i = t; i < cnt; i += 256) {
            unsigned u = bp[i];
            int ld = (int)((u >> 16) & (BUCK_W - 1));
            int slot = atomicAdd(&degS[ld], 1);           // LDS atomic
            colidx[slot] = (unsigned short)(u & 0xffffu);
        }
        return;
    }

    int t = (int)threadIdx.x;
    int wave = t >> 6, lane = t & 63;
    int mbase = blockIdx.x * 64 + wave * 16;
    int arow  = mbase + (lane & 15);
    if (arow >= N) arow = N - 1;             // clamped duplicate reads
    int kgrp  = lane >> 4;                   // 0..3

    // X-frag: lane holds X[arow][kt*32 + kgrp*8 .. +8], converted to fp16
    f16x8 afrag[4];
#pragma unroll
    for (int kt = 0; kt < 4; ++kt) {
        const float* xp = X + (size_t)arow * D + kt * 32 + kgrp * 8;
        float4 a0 = *(const float4*)xp;
        float4 a1 = *(const float4*)(xp + 4);
        f16x8 af;
        af[0] = (_Float16)a0.x; af[1] = (_Float16)a0.y;
        af[2] = (_Float16)a0.z; af[3] = (_Float16)a0.w;
        af[4] = (_Float16)a1.x; af[5] = (_Float16)a1.y;
        af[6] = (_Float16)a1.z; af[7] = (_Float16)a1.w;
        afrag[kt] = af;
    }
    f32x4 acc[8];
#pragma unroll
    for (int nt = 0; nt < 8; ++nt) acc[nt] = (f32x4){0.f, 0.f, 0.f, 0.f};
#pragma unroll
    for (int kt = 0; kt < 4; ++kt) {
#pragma unroll
        for (int nt = 0; nt < 8; ++nt) {
            uint4 u = *(const uint4*)(WB + (((kt * 8 + nt) * 64 + lane) * 8));
            f16x8 bfrag = __builtin_bit_cast(f16x8, u);
            // operand swap: A = W-frag, B = X-frag (same lane layouts serve
            // both roles). D: col(lane&15) = node, row(kgrp*4+r) = out col.
            acc[nt] = __builtin_amdgcn_mfma_f32_16x16x32_f16(bfrag, afrag[kt], acc[nt], 0, 0, 0);
        }
    }
    // C-write: lane owns node-row mbase+(lane&15); per nt, 4 consecutive
    // cols nt*16+kgrp*4+{0..3} -> one 8B store. [m89 C/D layout]
    int row = mbase + (lane & 15);
    if (row < N) {
        float dv = dinv[row];
#pragma unroll
        for (int nt = 0; nt < 8; ++nt) {
            uint2 w;
            w.x = f2h(dv * acc[nt][0], dv * acc[nt][1]);
            w.y = f2h(dv * acc[nt][2], dv * acc[nt][3]);
            *(uint2*)(Gh + (size_t)row * D + nt * 16 + kgrp * 4) = w;
        }
    }
}

// --- agg1: H''_i = dinv_i * relu(dinv_i*(sum_e G'_s + G'_i) + b1), fp16 -----
// 64-lane wave per node; padded CSR -> branchless 8-deep gather bursts.
__global__ __launch_bounds__(256) void agg1_kernel(const unsigned* __restrict__ Gh,
                                                   const int* __restrict__ rowstart,
                                                   const unsigned short* __restrict__ colidx,
                                                   const float* __restrict__ dinv,
                                                   const float* __restrict__ b1,
                                                   unsigned* __restrict__ Hh,
                                                   int N, int chunk) {
    int gid  = blockIdx.x * 4 + (threadIdx.x >> 6);
    unsigned lane = threadIdx.x & 63;
    int i0 = gid * chunk, i1 = min(i0 + chunk, N);
    float bx = b1[2 * lane], by = b1[2 * lane + 1];
    for (int i = i0; i < i1; ++i) {
        float di = dinv[i];
        float2 acc = h2f(Gh[((unsigned)i << 6) + lane]);    // self term
        int e0 = rowstart[i], e1 = rowstart[i + 1];         // both mult of 8
        for (int e = e0; e < e1; e += 8) {
            u16x8 cc = *(const u16x8*)(colidx + e);         // 16B, aligned
            unsigned u[8];
#pragma unroll
            for (int j = 0; j < 8; ++j)
                u[j] = Gh[((unsigned)cc[j] << 6) + lane];
#pragma unroll
            for (int j = 0; j < 8; ++j) {
                float2 v = h2f(u[j]);
                acc.x += v.x;
                acc.y += v.y;
            }
        }
        float hx = fmaxf(fmaf(di, acc.x, bx), 0.f) * di;    // H'' = dinv*relu
        float hy = fmaxf(fmaf(di, acc.y, by), 0.f) * di;
        Hh[((unsigned)i << 6) + lane] = f2h(hx, hy);
    }
}

// --- binary search for graph boundaries ------------------------------------
__device__ __forceinline__ int lbound(const int* __restrict__ a, int n, int v) {
    int lo = 0, hi = n;
    while (lo < hi) {
        int m = (lo + hi) >> 1;
        if (a[m] < v) lo = m + 1; else hi = m;
    }
    return lo;
}

// --- agg2 + pool + (last block) final GEMM ----------------------------------
// pool[batch_i] += dinv_i*(sum_e H''_s + H''_i); last ticket block computes
// out[g][o] = (pool[g]/cnt_g) . W2[:,o] + b2[o].
__global__ __launch_bounds__(256) void agg2_pool_kernel(const unsigned* __restrict__ Hh,
                                                        const int* __restrict__ rowstart,
                                                        const unsigned short* __restrict__ colidx,
                                                        const float* __restrict__ dinv,
                                                        const int* __restrict__ batch,
                                                        float* __restrict__ pool,
                                                        const float* __restrict__ W2,
                                                        const float* __restrict__ b2,
                                                        float* __restrict__ out,
                                                        int* __restrict__ ticket2,
                                                        int N, int chunk, int nblk) {
    int gid  = blockIdx.x * 4 + (threadIdx.x >> 6);
    unsigned lane = threadIdx.x & 63;
    int i0 = gid * chunk, i1 = min(i0 + chunk, N);

    if (i0 < N) {
        float2 pa = make_float2(0.f, 0.f);
        int cur = min(max(batch[i0], 0), NGRAPH - 1);
        for (int i = i0; i < i1; ++i) {
            float di = dinv[i];
            float2 a = h2f(Hh[((unsigned)i << 6) + lane]);  // self term
            int e0 = rowstart[i], e1 = rowstart[i + 1];
            for (int e = e0; e < e1; e += 8) {
                u16x8 cc = *(const u16x8*)(colidx + e);
                unsigned u[8];
#pragma unroll
                for (int j = 0; j < 8; ++j)
                    u[j] = Hh[((unsigned)cc[j] << 6) + lane];
#pragma unroll
                for (int j = 0; j < 8; ++j) {
                    float2 v = h2f(u[j]);
                    a.x += v.x;
                    a.y += v.y;
                }
            }
            int b = min(max(batch[i], 0), NGRAPH - 1);
            if (b != cur) {                                 // uniform per wave
                atomicAdd(&pool[(size_t)cur * D + 2 * lane], pa.x);
                atomicAdd(&pool[(size_t)cur * D + 2 * lane + 1], pa.y);
                pa = make_float2(0.f, 0.f);
                cur = b;
            }
            pa.x = fmaf(di, a.x, pa.x);
            pa.y = fmaf(di, a.y, pa.y);
        }
        atomicAdd(&pool[(size_t)cur * D + 2 * lane], pa.x);
        atomicAdd(&pool[(size_t)cur * D + 2 * lane + 1], pa.y);
    }

    // last-block ticket: ALL blocks tick (even empty ones) -> final GEMM
    __shared__ int lastF;
    __threadfence();
    if (threadIdx.x == 0)
        lastF = (atomicAdd(ticket2, 1) == nblk - 1) ? 1 : 0;
    __syncthreads();
    if (lastF) {
        __threadfence();                      // acquire all pool atomics
        int t = (int)threadIdx.x;
        for (int idx = t; idx < NGRAPH * D; idx += 256) {
            int g = idx >> 7, o = idx & 127;
            int s = lbound(batch, N, g);
            int e = lbound(batch, N, g + 1);
            float inv_cnt = 1.0f / fmaxf((float)(e - s), 1.0f);
            float acc = 0.f;
#pragma unroll 4
            for (int k = 0; k < D; ++k)
                acc = fmaf(pool[g * D + k], W2[k * D + o], acc);
            out[idx] = acc * inv_cnt + b2[o];
        }
    }
}

// ---------------------------------------------------------------------------

extern "C" void kernel_launch(void* const* d_in, const int* in_sizes, int n_in,
                              void* d_out, int out_size, void* d_ws, size_t ws_size,
                              hipStream_t stream) {
    const float* x     = (const float*)d_in[0];
    const int*   ei    = (const int*)  d_in[1];
    const int*   batch = (const int*)  d_in[2];
    const float* W1    = (const float*)d_in[3];
    const float* b1    = (const float*)d_in[4];
    const float* W2    = (const float*)d_in[5];
    const float* b2    = (const float*)d_in[6];
    float* out = (float*)d_out;

    const int N = in_sizes[0] / D;
    const int E = in_sizes[1] / 2;
    const int nbuck = (N + BUCK_W - 1) >> BUCK_SH;      // <=128 for N<=65536
    const int CAP   = (E / (nbuck > 0 ? nbuck : 1)) * 2 + 1024;

    // workspace carve-up (256B aligned); bcnt+pool+tickets -> single memset
    char* ws = (char*)d_ws;
    size_t off = 0;
    auto carve = [&](size_t bytes) {
        size_t o = off;
        off = (off + bytes + 255) & ~(size_t)255;
        return o;
    };
    size_t o_bcnt     = carve((size_t)MAXBUCK * 4);
    size_t o_pool     = carve((size_t)NGRAPH * D * 4);
    size_t o_ticket   = carve((size_t)256);        // bucket_deg ticket
    size_t o_ticket2  = carve((size_t)256);        // agg2 ticket
    size_t zspan      = off;                       // memset [0, zspan)
    size_t o_rowstart = carve((size_t)(N + 1) * 4);
    size_t o_deg      = carve((size_t)N * 4);
    size_t o_dinv     = carve((size_t)N * 4);
    size_t o_padsum   = carve((size_t)MAXBUCK * 4);
    size_t o_bbase    = carve((size_t)MAXBUCK * 4);
    size_t o_colidx   = carve(((size_t)E + 7 * (size_t)N + 64) * 2);  // padded
    size_t o_buck     = carve((size_t)nbuck * CAP * 4);
    size_t o_wb       = carve((size_t)D * D * 2);        // fp16 W1 (MFMA B)
    size_t o_gh       = carve((size_t)(N + 1) * D * 2);  // fp16 G' (+zero row)
    size_t o_hh       = carve((size_t)(N + 1) * D * 2);  // fp16 H'' (+zero row)
    size_t need = off;

    if (ws_size < need) {
        zero_out_kernel<<<(out_size + 255) / 256, 256, 0, stream>>>(out, out_size);
        return;
    }

    int*            bcnt     = (int*)           (ws + o_bcnt);
    float*          pool     = (float*)         (ws + o_pool);
    int*            ticket   = (int*)           (ws + o_ticket);
    int*            ticket2  = (int*)           (ws + o_ticket2);
    int*            rowstart = (int*)           (ws + o_rowstart);
    int*            deg      = (int*)           (ws + o_deg);
    float*          dinv     = (float*)         (ws + o_dinv);
    int*            padsum   = (int*)           (ws + o_padsum);
    int*            bbase    = (int*)           (ws + o_bbase);
    unsigned short* colidx   = (unsigned short*)(ws + o_colidx);
    unsigned*       buck     = (unsigned*)      (ws + o_buck);
    _Float16*       WB       = (_Float16*)      (ws + o_wb);
    _Float16*       Gh       = (_Float16*)      (ws + o_gh);
    _Float16*       Hh       = (_Float16*)      (ws + o_hh);

    hipMemsetAsync(ws, 0, zspan, stream);          // bcnt + pool + tickets

    int ebs = (E + 1023) / 1024;                   // scatter: 4 edges/thread
    int gb  = (N + 63) / 64;

    pack_scatter_kernel<<<9 + ebs, 256, 0, stream>>>(W1, WB, ei, bcnt, buck,
                                                     (unsigned*)Gh, (unsigned*)Hh,
                                                     N, E, CAP);
    bucket_deg_kernel<<<nbuck, 256, 0, stream>>>(buck, bcnt, deg, dinv, padsum,
                                                 bbase, rowstart, ticket,
                                                 N, CAP, nbuck);
    gemm_fill_kernel<<<gb + nbuck, 256, 0, stream>>>(x, WB, dinv, Gh, buck, bcnt,
                                                     deg, bbase, rowstart, colidx,
                                                     N, CAP, gb);

    int groups = AGG_BLOCKS * 4;
    int chunk  = (N + groups - 1) / groups;
    agg1_kernel<<<AGG_BLOCKS, 256, 0, stream>>>((const unsigned*)Gh, rowstart, colidx,
                                                dinv, b1, (unsigned*)Hh, N, chunk);
    agg2_pool_kernel<<<AGG_BLOCKS, 256, 0, stream>>>((const unsigned*)Hh, rowstart, colidx,
                                                     dinv, batch, pool, W2, b2, out,
                                                     ticket2, N, chunk, AGG_BLOCKS);
}

// Round 10
// 206.400 us; speedup vs baseline: 3.1587x; 3.1587x over previous
//
#include <hip/hip_runtime.h>

// ---------------------------------------------------------------------------
// 2-layer GCN + global mean pool, MI355X (gfx950).
//   A_hat = D^{-1/2}(A+I)D^{-1/2}
//   G' = dinv*(X @ W1) fp16 [MFMA fp16];  H'' = dinv*relu(dinv*A_sum(G')+b1)
//   out = pool(dinv*A_sum(H'')) @ W2 + b2
// R20 = R14 agg structure (best, 196us) + operand-swapped GEMM (isolated).
//   R19 post-mortem: per-block __threadfence() in agg2 = L2 WB/INV on
//   non-coherent XCD L2s -> destroyed gather locality (FETCH 21->65MB,
//   500us). NEVER fence on the hot path of cache-dependent kernels.
//   agg2+final fusion REVERTED (separate final_gemm launch, no fences).
//   Kept: (1) mfma(A=WB, B=Xfrag) swap -> lane owns node-row, C-write =
//   8 x 8B contiguous stores (was 32 x 2B scattered); zero repack, same
//   math. (2) ticket-fused bucket scan (R17-verified; fence confined to
//   128 small blocks). CSR: two-level sort, no per-edge global atomics.
// ws_size is 256 MiB; we use ~35 MB.
// ---------------------------------------------------------------------------

#define D 128
#define NGRAPH 64
#define AGG_BLOCKS 2048   // 8192 waves = 32/CU
#define BUCK_SH 9         // bucket = dst >> 9 (width 512)
#define BUCK_W  512
#define MAXBUCK 128       // N <= 65536

typedef _Float16 h16x2 __attribute__((ext_vector_type(2)));
typedef _Float16 f16x8 __attribute__((ext_vector_type(8)));
typedef float    f32x4 __attribute__((ext_vector_type(4)));
typedef unsigned short u16x8 __attribute__((ext_vector_type(8)));

__device__ __forceinline__ float2 h2f(unsigned u) {
    h16x2 h = __builtin_bit_cast(h16x2, u);
    return make_float2((float)h.x, (float)h.y);
}
__device__ __forceinline__ unsigned f2h(float x, float y) {
    h16x2 h;
    h.x = (_Float16)x;
    h.y = (_Float16)y;
    return __builtin_bit_cast(unsigned, h);
}

// --- diagnostic: all-zero output (ws too small) ----------------------------
__global__ void zero_out_kernel(float* __restrict__ out, int n) {
    int i = blockIdx.x * blockDim.x + threadIdx.x;
    if (i < n) out[i] = 0.f;
}

// --- K1: W1 pack (blocks 0..7) | zero sentinel rows (block 8) | bucket
//     scatter (blocks 9..): LDS histogram + per-block span reservation. -----
__global__ __launch_bounds__(256) void pack_scatter_kernel(const float* __restrict__ W1,
                                                           _Float16* __restrict__ WB,
                                                           const int* __restrict__ ei,
                                                           int* __restrict__ bcnt,
                                                           unsigned* __restrict__ buck,
                                                           unsigned* __restrict__ Gz,
                                                           unsigned* __restrict__ Hz,
                                                           int N, int E, int CAP) {
    int b = (int)blockIdx.x;
    int t = (int)threadIdx.x;
    if (b < 8) {
        // WB[((kt*8+nt)*64+lane)*8+j] = W1[(kt*32+(lane>>4)*8+j)*D + nt*16+(lane&15)]
        int idx = b * 256 + t;                         // 0..2047
        int lane = idx & 63;
        int nt   = (idx >> 6) & 7;
        int kt   = idx >> 9;
        int col  = nt * 16 + (lane & 15);
        int krow = kt * 32 + (lane >> 4) * 8;
#pragma unroll
        for (int j = 0; j < 8; ++j)
            WB[idx * 8 + j] = (_Float16)W1[(krow + j) * D + col];
        return;
    }
    if (b == 8) {
        if (t < 64)       Gz[(size_t)N * 64 + t] = 0u;          // Gh row N = 0
        else if (t < 128) Hz[(size_t)N * 64 + (t - 64)] = 0u;   // Hh row N = 0
        return;
    }
    __shared__ unsigned histL[MAXBUCK];
    __shared__ int      baseL[MAXBUCK];
    if (t < MAXBUCK) histL[t] = 0u;
    __syncthreads();

    int e0 = (b - 9) * 1024;
    int bid[4];
    unsigned lidx[4], pk[4];
#pragma unroll
    for (int j = 0; j < 4; ++j) {
        int e = e0 + t + j * 256;
        bid[j] = -1;
        if (e < E) {
            int s = ei[e];
            int d = ei[E + e];
            if (d >= 0 && d < N) {
                s = min(max(s, 0), N - 1);
                bid[j] = d >> BUCK_SH;
                pk[j]  = ((unsigned)d << 16) | (unsigned)s;
            }
        }
    }
#pragma unroll
    for (int j = 0; j < 4; ++j)
        if (bid[j] >= 0) lidx[j] = atomicAdd(&histL[bid[j]], 1u);
    __syncthreads();
    if (t < MAXBUCK && histL[t] > 0u)
        baseL[t] = atomicAdd(&bcnt[t], (int)histL[t]);
    __syncthreads();
#pragma unroll
    for (int j = 0; j < 4; ++j)
        if (bid[j] >= 0) {
            int slot = baseL[bid[j]] + (int)lidx[j];
            if (slot < CAP) buck[(size_t)bid[j] * CAP + slot] = pk[j];
        }
}

// --- K2: per-bucket degree count (LDS atomics) -> deg, dinv, padsum;
//     LAST block (ticket) also scans padsums -> bbase, rowstart[N]. ---------
__global__ __launch_bounds__(256) void bucket_deg_kernel(const unsigned* __restrict__ buck,
                                                         const int* __restrict__ bcnt,
                                                         int* __restrict__ deg,
                                                         float* __restrict__ dinv,
                                                         int* __restrict__ padsum,
                                                         int* __restrict__ bbase,
                                                         int* __restrict__ rowstart,
                                                         int* __restrict__ ticket,
                                                         int N, int CAP, int nbuck) {
    __shared__ int degL[BUCK_W];
    __shared__ int red[256];
    __shared__ int lastFlag;
    int b = (int)blockIdx.x;
    int t = (int)threadIdx.x;
    for (int k = t; k < BUCK_W; k += 256) degL[k] = 0;
    __syncthreads();
    int cnt = min(bcnt[b], CAP);
    const unsigned* bp = buck + (size_t)b * CAP;
    for (int i = t; i < cnt; i += 256)
        atomicAdd(&degL[(bp[i] >> 16) & (BUCK_W - 1)], 1);
    __syncthreads();
    int base = b << BUCK_SH;
    int local = 0;
    for (int k = t; k < BUCK_W; k += 256) {
        int d = base + k;
        if (d < N) {
            int dg = degL[k];
            deg[d]  = dg;
            dinv[d] = rsqrtf((float)dg + 1.0f);
            local  += (dg + 7) & ~7;
        }
    }
    red[t] = local;
    __syncthreads();
    for (int off = 128; off > 0; off >>= 1) {
        if (t < off) red[t] += red[t + off];
        __syncthreads();
    }
    if (t == 0) padsum[b] = red[0];
    __threadfence();
    if (t == 0) lastFlag = (atomicAdd(ticket, 1) == nbuck - 1) ? 1 : 0;
    __syncthreads();
    if (lastFlag) {
        __threadfence();                     // acquire all padsum writes
        __shared__ int s[128];
        int own = (t < nbuck) ? padsum[t] : 0;
        if (t < 128) s[t] = own;
        __syncthreads();
        for (int off = 1; off < 128; off <<= 1) {
            int v = (t < 128 && t >= off) ? s[t - off] : 0;
            __syncthreads();
            if (t < 128) s[t] += v;
            __syncthreads();
        }
        if (t < nbuck) bbase[t] = s[t] - own;        // exclusive
        if (t == 127) rowstart[N] = s[127];
    }
}

// --- K3: fused MFMA GEMM (blocks [0,gb)) + bucket CSR fill ([gb,gb+nbuck)) -
// GEMM: operand-swapped mfma -> lane owns node-row, 8 x 8B C-stores.
// Fill: per-bucket LDS scan of padded degrees -> rowstart; sentinel pads;
// colidx placement via LDS cursors. Zero global atomics.
__global__ __launch_bounds__(256) void gemm_fill_kernel(const float* __restrict__ X,
                                                        const _Float16* __restrict__ WB,
                                                        const float* __restrict__ dinv,
                                                        _Float16* __restrict__ Gh,
                                                        const unsigned* __restrict__ buck,
                                                        const int* __restrict__ bcnt,
                                                        const int* __restrict__ deg,
                                                        const int* __restrict__ bbase,
                                                        int* __restrict__ rowstart,
                                                        unsigned short* __restrict__ colidx,
                                                        int N, int CAP, int gb) {
    if ((int)blockIdx.x >= gb) {
        __shared__ int degS[BUCK_W];    // deg, later absolute cursors
        __shared__ int loff[BUCK_W];
        __shared__ int sc[256];
        int b = (int)blockIdx.x - gb;
        int t = (int)threadIdx.x;
        int base_d = b << BUCK_SH;
        for (int k = t; k < BUCK_W; k += 256) {
            int d = base_d + k;
            degS[k] = (d < N) ? deg[d] : 0;
        }
        __syncthreads();
        // scan pad8 over 512 entries: thread t owns 2t, 2t+1
        int p0 = (degS[2 * t] + 7) & ~7;
        int p1 = (degS[2 * t + 1] + 7) & ~7;
        int own = p0 + p1;
        sc[t] = own;
        __syncthreads();
        for (int off = 1; off < 256; off <<= 1) {
            int v = (t >= off) ? sc[t - off] : 0;
            __syncthreads();
            sc[t] += v;
            __syncthreads();
        }
        int excl = sc[t] - own;
        loff[2 * t]     = excl;
        loff[2 * t + 1] = excl + p0;
        __syncthreads();
        int bb = bbase[b];
        // rowstart + sentinel pads (uses degS as degrees still)
        for (int k = t; k < BUCK_W; k += 256) {
            int d = base_d + k;
            if (d < N) {
                int rs = bb + loff[k];
                rowstart[d] = rs;
                int dg = degS[k];
                int p8 = (dg + 7) & ~7;
                for (int j = dg; j < p8; ++j)
                    colidx[rs + j] = (unsigned short)N;   // sentinel -> zero row
            }
        }
        __syncthreads();
        // convert degS -> absolute cursors
        for (int k = t; k < BUCK_W; k += 256) degS[k] = bb + loff[k];
        __syncthreads();
        int cnt = min(bcnt[b], CAP);
        const unsigned* bp = buck + (size_t)b * CAP;
        for (int i = t; i < cnt; i += 256) {
            unsigned u = bp[i];
            int ld = (int)((u >> 16) & (BUCK_W - 1));
            int slot = atomicAdd(&degS[ld], 1);           // LDS atomic
            colidx[slot] = (unsigned short)(u & 0xffffu);
        }
        return;
    }

    int t = (int)threadIdx.x;
    int wave = t >> 6, lane = t & 63;
    int mbase = blockIdx.x * 64 + wave * 16;
    int arow  = mbase + (lane & 15);
    if (arow >= N) arow = N - 1;             // clamped duplicate reads
    int kgrp  = lane >> 4;                   // 0..3

    // X-frag: lane holds X[arow][kt*32 + kgrp*8 .. +8], converted to fp16
    f16x8 afrag[4];
#pragma unroll
    for (int kt = 0; kt < 4; ++kt) {
        const float* xp = X + (size_t)arow * D + kt * 32 + kgrp * 8;
        float4 a0 = *(const float4*)xp;
        float4 a1 = *(const float4*)(xp + 4);
        f16x8 af;
        af[0] = (_Float16)a0.x; af[1] = (_Float16)a0.y;
        af[2] = (_Float16)a0.z; af[3] = (_Float16)a0.w;
        af[4] = (_Float16)a1.x; af[5] = (_Float16)a1.y;
        af[6] = (_Float16)a1.z; af[7] = (_Float16)a1.w;
        afrag[kt] = af;
    }
    f32x4 acc[8];
#pragma unroll
    for (int nt = 0; nt < 8; ++nt) acc[nt] = (f32x4){0.f, 0.f, 0.f, 0.f};
#pragma unroll
    for (int kt = 0; kt < 4; ++kt) {
#pragma unroll
        for (int nt = 0; nt < 8; ++nt) {
            uint4 u = *(const uint4*)(WB + (((kt * 8 + nt) * 64 + lane) * 8));
            f16x8 bfrag = __builtin_bit_cast(f16x8, u);
            // operand swap: A = W-frag, B = X-frag (same lane layouts serve
            // both roles). D: col(lane&15) = node, row(kgrp*4+r) = out col.
            acc[nt] = __builtin_amdgcn_mfma_f32_16x16x32_f16(bfrag, afrag[kt], acc[nt], 0, 0, 0);
        }
    }
    // C-write: lane owns node-row mbase+(lane&15); per nt, 4 consecutive
    // cols nt*16+kgrp*4+{0..3} -> one 8B store. [m89 C/D layout]
    int row = mbase + (lane & 15);
    if (row < N) {
        float dv = dinv[row];
#pragma unroll
        for (int nt = 0; nt < 8; ++nt) {
            uint2 w;
            w.x = f2h(dv * acc[nt][0], dv * acc[nt][1]);
            w.y = f2h(dv * acc[nt][2], dv * acc[nt][3]);
            *(uint2*)(Gh + (size_t)row * D + nt * 16 + kgrp * 4) = w;
        }
    }
}

// --- agg1: H''_i = dinv_i * relu(dinv_i*(sum_e G'_s + G'_i) + b1), fp16 -----
// 64-lane wave per node; padded CSR -> branchless 8-deep gather bursts.
__global__ __launch_bounds__(256) void agg1_kernel(const unsigned* __restrict__ Gh,
                                                   const int* __restrict__ rowstart,
                                                   const unsigned short* __restrict__ colidx,
                                                   const float* __restrict__ dinv,
                                                   const float* __restrict__ b1,
                                                   unsigned* __restrict__ Hh,
                                                   int N, int chunk) {
    int gid  = blockIdx.x * 4 + (threadIdx.x >> 6);
    unsigned lane = threadIdx.x & 63;
    int i0 = gid * chunk, i1 = min(i0 + chunk, N);
    float bx = b1[2 * lane], by = b1[2 * lane + 1];
    for (int i = i0; i < i1; ++i) {
        float di = dinv[i];
        float2 acc = h2f(Gh[((unsigned)i << 6) + lane]);    // self term
        int e0 = rowstart[i], e1 = rowstart[i + 1];         // both mult of 8
        for (int e = e0; e < e1; e += 8) {
            u16x8 cc = *(const u16x8*)(colidx + e);         // 16B, aligned
            unsigned u[8];
#pragma unroll
            for (int j = 0; j < 8; ++j)
                u[j] = Gh[((unsigned)cc[j] << 6) + lane];
#pragma unroll
            for (int j = 0; j < 8; ++j) {
                float2 v = h2f(u[j]);
                acc.x += v.x;
                acc.y += v.y;
            }
        }
        float hx = fmaxf(fmaf(di, acc.x, bx), 0.f) * di;    // H'' = dinv*relu
        float hy = fmaxf(fmaf(di, acc.y, by), 0.f) * di;
        Hh[((unsigned)i << 6) + lane] = f2h(hx, hy);
    }
}

// --- agg2 + pool: pool[batch_i] += dinv_i*(sum_e H''_s + H''_i) -------------
__global__ __launch_bounds__(256) void agg2_pool_kernel(const unsigned* __restrict__ Hh,
                                                        const int* __restrict__ rowstart,
                                                        const unsigned short* __restrict__ colidx,
                                                        const float* __restrict__ dinv,
                                                        const int* __restrict__ batch,
                                                        float* __restrict__ pool,
                                                        int N, int chunk) {
    int gid  = blockIdx.x * 4 + (threadIdx.x >> 6);
    unsigned lane = threadIdx.x & 63;
    int i0 = gid * chunk, i1 = min(i0 + chunk, N);
    if (i0 >= N) return;

    float2 pa = make_float2(0.f, 0.f);
    int cur = min(max(batch[i0], 0), NGRAPH - 1);
    for (int i = i0; i < i1; ++i) {
        float di = dinv[i];
        float2 a = h2f(Hh[((unsigned)i << 6) + lane]);      // self term
        int e0 = rowstart[i], e1 = rowstart[i + 1];
        for (int e = e0; e < e1; e += 8) {
            u16x8 cc = *(const u16x8*)(colidx + e);
            unsigned u[8];
#pragma unroll
            for (int j = 0; j < 8; ++j)
                u[j] = Hh[((unsigned)cc[j] << 6) + lane];
#pragma unroll
            for (int j = 0; j < 8; ++j) {
                float2 v = h2f(u[j]);
                a.x += v.x;
                a.y += v.y;
            }
        }
        int b = min(max(batch[i], 0), NGRAPH - 1);
        if (b != cur) {                                     // uniform per wave
            atomicAdd(&pool[(size_t)cur * D + 2 * lane], pa.x);
            atomicAdd(&pool[(size_t)cur * D + 2 * lane + 1], pa.y);
            pa = make_float2(0.f, 0.f);
            cur = b;
        }
        pa.x = fmaf(di, a.x, pa.x);
        pa.y = fmaf(di, a.y, pa.y);
    }
    atomicAdd(&pool[(size_t)cur * D + 2 * lane], pa.x);
    atomicAdd(&pool[(size_t)cur * D + 2 * lane + 1], pa.y);
}

// --- Final tiny GEMM: out[g][o] = (pool[g]/cnt_g) . W2[:,o] + b2[o] ---------
__device__ __forceinline__ int lbound(const int* __restrict__ a, int n, int v) {
    int lo = 0, hi = n;
    while (lo < hi) {
        int m = (lo + hi) >> 1;
        if (a[m] < v) lo = m + 1; else hi = m;
    }
    return lo;
}

__global__ void final_gemm_kernel(const float* __restrict__ pool,
                                  const int* __restrict__ batch,
                                  const float* __restrict__ W2,
                                  const float* __restrict__ b2,
                                  float* __restrict__ out, int N) {
    int g = blockIdx.x, o = threadIdx.x;
    int s = lbound(batch, N, g);
    int e = lbound(batch, N, g + 1);
    float inv_cnt = 1.0f / fmaxf((float)(e - s), 1.0f);
    float acc = 0.f;
#pragma unroll 4
    for (int k = 0; k < D; ++k)
        acc = fmaf(pool[g * D + k], W2[k * D + o], acc);
    out[g * D + o] = acc * inv_cnt + b2[o];
}

// ---------------------------------------------------------------------------

extern "C" void kernel_launch(void* const* d_in, const int* in_sizes, int n_in,
                              void* d_out, int out_size, void* d_ws, size_t ws_size,
                              hipStream_t stream) {
    const float* x     = (const float*)d_in[0];
    const int*   ei    = (const int*)  d_in[1];
    const int*   batch = (const int*)  d_in[2];
    const float* W1    = (const float*)d_in[3];
    const float* b1    = (const float*)d_in[4];
    const float* W2    = (const float*)d_in[5];
    const float* b2    = (const float*)d_in[6];
    float* out = (float*)d_out;

    const int N = in_sizes[0] / D;
    const int E = in_sizes[1] / 2;
    const int nbuck = (N + BUCK_W - 1) >> BUCK_SH;      // <=128 for N<=65536
    const int CAP   = (E / (nbuck > 0 ? nbuck : 1)) * 2 + 1024;

    // workspace carve-up (256B aligned); bcnt+pool+ticket -> single memset
    char* ws = (char*)d_ws;
    size_t off = 0;
    auto carve = [&](size_t bytes) {
        size_t o = off;
        off = (off + bytes + 255) & ~(size_t)255;
        return o;
    };
    size_t o_bcnt     = carve((size_t)MAXBUCK * 4);
    size_t o_pool     = carve((size_t)NGRAPH * D * 4);
    size_t o_ticket   = carve((size_t)256);
    size_t zspan      = off;                       // memset [0, zspan)
    size_t o_rowstart = carve((size_t)(N + 1) * 4);
    size_t o_deg      = carve((size_t)N * 4);
    size_t o_dinv     = carve((size_t)N * 4);
    size_t o_padsum   = carve((size_t)MAXBUCK * 4);
    size_t o_bbase    = carve((size_t)MAXBUCK * 4);
    size_t o_colidx   = carve(((size_t)E + 7 * (size_t)N + 64) * 2);  // padded
    size_t o_buck     = carve((size_t)nbuck * CAP * 4);
    size_t o_wb       = carve((size_t)D * D * 2);        // fp16 W1 (MFMA B)
    size_t o_gh       = carve((size_t)(N + 1) * D * 2);  // fp16 G' (+zero row)
    size_t o_hh       = carve((size_t)(N + 1) * D * 2);  // fp16 H'' (+zero row)
    size_t need = off;

    if (ws_size < need) {
        zero_out_kernel<<<(out_size + 255) / 256, 256, 0, stream>>>(out, out_size);
        return;
    }

    int*            bcnt     = (int*)           (ws + o_bcnt);
    float*          pool     = (float*)         (ws + o_pool);
    int*            ticket   = (int*)           (ws + o_ticket);
    int*            rowstart = (int*)           (ws + o_rowstart);
    int*            deg      = (int*)           (ws + o_deg);
    float*          dinv     = (float*)         (ws + o_dinv);
    int*            padsum   = (int*)           (ws + o_padsum);
    int*            bbase    = (int*)           (ws + o_bbase);
    unsigned short* colidx   = (unsigned short*)(ws + o_colidx);
    unsigned*       buck     = (unsigned*)      (ws + o_buck);
    _Float16*       WB       = (_Float16*)      (ws + o_wb);
    _Float16*       Gh       = (_Float16*)      (ws + o_gh);
    _Float16*       Hh       = (_Float16*)      (ws + o_hh);

    hipMemsetAsync(ws, 0, zspan, stream);          // bcnt + pool + ticket

    int ebs = (E + 1023) / 1024;                   // scatter: 4 edges/thread
    int gb  = (N + 63) / 64;

    pack_scatter_kernel<<<9 + ebs, 256, 0, stream>>>(W1, WB, ei, bcnt, buck,
                                                     (unsigned*)Gh, (unsigned*)Hh,
                                                     N, E, CAP);
    bucket_deg_kernel<<<nbuck, 256, 0, stream>>>(buck, bcnt, deg, dinv, padsum,
                                                 bbase, rowstart, ticket,
                                                 N, CAP, nbuck);
    gemm_fill_kernel<<<gb + nbuck, 256, 0, stream>>>(x, WB, dinv, Gh, buck, bcnt,
                                                     deg, bbase, rowstart, colidx,
                                                     N, CAP, gb);

    int groups = AGG_BLOCKS * 4;
    int chunk  = (N + groups - 1) / groups;
    agg1_kernel<<<AGG_BLOCKS, 256, 0, stream>>>((const unsigned*)Gh, rowstart, colidx,
                                                dinv, b1, (unsigned*)Hh, N, chunk);
    agg2_pool_kernel<<<AGG_BLOCKS, 256, 0, stream>>>((const unsigned*)Hh, rowstart, colidx,
                                                     dinv, batch, pool, N, chunk);
    final_gemm_kernel<<<NGRAPH, D, 0, stream>>>(pool, batch, W2, b2, out, N);
}

// Round 11
// 199.812 us; speedup vs baseline: 3.2628x; 1.0330x over previous
//
#include <hip/hip_runtime.h>

// ---------------------------------------------------------------------------
// 2-layer GCN + global mean pool, MI355X (gfx950).
//   A_hat = D^{-1/2}(A+I)D^{-1/2}
//   G' = dinv*(X @ W1) fp16 [MFMA fp16];  H'' = dinv*relu(dinv*A_sum(G')+b1)
//   out = pool(dinv*A_sum(H'')) @ W2 + b2
// R21 = R14 exact structure (best, 196us; R20 operand swap reverted) + two
//   fill-tail fixes (R20 post-mortem: gemm_fill 47us with ALL pipes idle ->
//   the 128 fill blocks at the END of the grid run as a serial tail):
//   (1) fill blocks FIRST in the grid ([0,nbuck)) -> tail overlaps GEMM.
//   (2) BUCK_SH 9->8: 196 buckets x 256 nodes -> 2x fill/deg parallelism,
//       half the per-block serial edge count; fill scan = 1 entry/thread.
//   Aggs: R14 code exactly (at the LLC random-line wall, ~45-50us each —
//   resistant to 6 distinct optimizations across R15-R20).
//   CSR build: two-level counting sort, zero per-edge global atomics;
//   ticket-fused bucket scan (fence confined to the 196 small deg blocks).
// ws_size is 256 MiB; we use ~36 MB.
// ---------------------------------------------------------------------------

#define D 128
#define NGRAPH 64
#define AGG_BLOCKS 2048   // 8192 waves = 32/CU
#define BUCK_SH 8         // bucket = dst >> 8 (width 256)
#define BUCK_W  256
#define MAXBUCK 256       // N <= 65536

typedef _Float16 h16x2 __attribute__((ext_vector_type(2)));
typedef _Float16 f16x8 __attribute__((ext_vector_type(8)));
typedef float    f32x4 __attribute__((ext_vector_type(4)));
typedef unsigned short u16x8 __attribute__((ext_vector_type(8)));

__device__ __forceinline__ float2 h2f(unsigned u) {
    h16x2 h = __builtin_bit_cast(h16x2, u);
    return make_float2((float)h.x, (float)h.y);
}
__device__ __forceinline__ unsigned f2h(float x, float y) {
    h16x2 h;
    h.x = (_Float16)x;
    h.y = (_Float16)y;
    return __builtin_bit_cast(unsigned, h);
}

// --- diagnostic: all-zero output (ws too small) ----------------------------
__global__ void zero_out_kernel(float* __restrict__ out, int n) {
    int i = blockIdx.x * blockDim.x + threadIdx.x;
    if (i < n) out[i] = 0.f;
}

// --- K1: W1 pack (blocks 0..7) | zero sentinel rows (block 8) | bucket
//     scatter (blocks 9..): LDS histogram + per-block span reservation. -----
__global__ __launch_bounds__(256) void pack_scatter_kernel(const float* __restrict__ W1,
                                                           _Float16* __restrict__ WB,
                                                           const int* __restrict__ ei,
                                                           int* __restrict__ bcnt,
                                                           unsigned* __restrict__ buck,
                                                           unsigned* __restrict__ Gz,
                                                           unsigned* __restrict__ Hz,
                                                           int N, int E, int CAP) {
    int b = (int)blockIdx.x;
    int t = (int)threadIdx.x;
    if (b < 8) {
        // WB[((kt*8+nt)*64+lane)*8+j] = W1[(kt*32+(lane>>4)*8+j)*D + nt*16+(lane&15)]
        int idx = b * 256 + t;                         // 0..2047
        int lane = idx & 63;
        int nt   = (idx >> 6) & 7;
        int kt   = idx >> 9;
        int col  = nt * 16 + (lane & 15);
        int krow = kt * 32 + (lane >> 4) * 8;
#pragma unroll
        for (int j = 0; j < 8; ++j)
            WB[idx * 8 + j] = (_Float16)W1[(krow + j) * D + col];
        return;
    }
    if (b == 8) {
        if (t < 64)       Gz[(size_t)N * 64 + t] = 0u;          // Gh row N = 0
        else if (t < 128) Hz[(size_t)N * 64 + (t - 64)] = 0u;   // Hh row N = 0
        return;
    }
    __shared__ unsigned histL[MAXBUCK];
    __shared__ int      baseL[MAXBUCK];
    histL[t] = 0u;                             // MAXBUCK == 256 == blockDim
    __syncthreads();

    int e0 = (b - 9) * 1024;
    int bid[4];
    unsigned lidx[4], pk[4];
#pragma unroll
    for (int j = 0; j < 4; ++j) {
        int e = e0 + t + j * 256;
        bid[j] = -1;
        if (e < E) {
            int s = ei[e];
            int d = ei[E + e];
            if (d >= 0 && d < N) {
                s = min(max(s, 0), N - 1);
                bid[j] = d >> BUCK_SH;
                pk[j]  = ((unsigned)d << 16) | (unsigned)s;
            }
        }
    }
#pragma unroll
    for (int j = 0; j < 4; ++j)
        if (bid[j] >= 0) lidx[j] = atomicAdd(&histL[bid[j]], 1u);
    __syncthreads();
    if (histL[t] > 0u)
        baseL[t] = atomicAdd(&bcnt[t], (int)histL[t]);
    __syncthreads();
#pragma unroll
    for (int j = 0; j < 4; ++j)
        if (bid[j] >= 0) {
            int slot = baseL[bid[j]] + (int)lidx[j];
            if (slot < CAP) buck[(size_t)bid[j] * CAP + slot] = pk[j];
        }
}

// --- K2: per-bucket degree count (LDS atomics) -> deg, dinv, padsum;
//     LAST block (ticket) also scans padsums -> bbase, rowstart[N]. ---------
__global__ __launch_bounds__(256) void bucket_deg_kernel(const unsigned* __restrict__ buck,
                                                         const int* __restrict__ bcnt,
                                                         int* __restrict__ deg,
                                                         float* __restrict__ dinv,
                                                         int* __restrict__ padsum,
                                                         int* __restrict__ bbase,
                                                         int* __restrict__ rowstart,
                                                         int* __restrict__ ticket,
                                                         int N, int CAP, int nbuck) {
    __shared__ int degL[BUCK_W];
    __shared__ int red[256];
    __shared__ int lastFlag;
    int b = (int)blockIdx.x;
    int t = (int)threadIdx.x;
    degL[t] = 0;                               // BUCK_W == 256 == blockDim
    __syncthreads();
    int cnt = min(bcnt[b], CAP);
    const unsigned* bp = buck + (size_t)b * CAP;
    for (int i = t; i < cnt; i += 256)
        atomicAdd(&degL[(bp[i] >> 16) & (BUCK_W - 1)], 1);
    __syncthreads();
    int base = b << BUCK_SH;
    int d = base + t;
    int local = 0;
    if (d < N) {
        int dg = degL[t];
        deg[d]  = dg;
        dinv[d] = rsqrtf((float)dg + 1.0f);
        local   = (dg + 7) & ~7;
    }
    red[t] = local;
    __syncthreads();
    for (int off = 128; off > 0; off >>= 1) {
        if (t < off) red[t] += red[t + off];
        __syncthreads();
    }
    if (t == 0) padsum[b] = red[0];
    __threadfence();
    if (t == 0) lastFlag = (atomicAdd(ticket, 1) == nbuck - 1) ? 1 : 0;
    __syncthreads();
    if (lastFlag) {
        __threadfence();                     // acquire all padsum writes
        __shared__ int s[256];
        int own = (t < nbuck) ? padsum[t] : 0;
        s[t] = own;
        __syncthreads();
        for (int off = 1; off < 256; off <<= 1) {
            int v = (t >= off) ? s[t - off] : 0;
            __syncthreads();
            s[t] += v;
            __syncthreads();
        }
        if (t < nbuck) bbase[t] = s[t] - own;        // exclusive
        if (t == 255) rowstart[N] = s[255];
    }
}

// --- K3: bucket CSR fill (blocks [0,nbuck) — FIRST so the tail overlaps)
//     + fused MFMA GEMM (blocks [nbuck, nbuck+gb)).
// Fill: per-bucket LDS scan of padded degrees -> rowstart; sentinel pads;
// colidx placement via LDS cursors. Zero global atomics.
__global__ __launch_bounds__(256) void gemm_fill_kernel(const float* __restrict__ X,
                                                        const _Float16* __restrict__ WB,
                                                        const float* __restrict__ dinv,
                                                        _Float16* __restrict__ Gh,
                                                        const unsigned* __restrict__ buck,
                                                        const int* __restrict__ bcnt,
                                                        const int* __restrict__ deg,
                                                        const int* __restrict__ bbase,
                                                        int* __restrict__ rowstart,
                                                        unsigned short* __restrict__ colidx,
                                                        int N, int CAP, int nbuck) {
    int t = (int)threadIdx.x;
    if ((int)blockIdx.x < nbuck) {
        __shared__ int curS[BUCK_W];    // absolute cursors
        __shared__ int sc[256];
        int b = (int)blockIdx.x;
        int base_d = b << BUCK_SH;
        int d = base_d + t;
        int dg = (d < N) ? deg[d] : 0;
        int p8 = (dg + 7) & ~7;
        // exclusive scan of pad8 (one entry per thread)
        sc[t] = p8;
        __syncthreads();
        for (int off = 1; off < 256; off <<= 1) {
            int v = (t >= off) ? sc[t - off] : 0;
            __syncthreads();
            sc[t] += v;
            __syncthreads();
        }
        int rs = bbase[b] + sc[t] - p8;
        if (d < N) {
            rowstart[d] = rs;
            for (int j = dg; j < p8; ++j)
                colidx[rs + j] = (unsigned short)N;   // sentinel -> zero row
        }
        curS[t] = rs;
        __syncthreads();
        int cnt = min(bcnt[b], CAP);
        const unsigned* bp = buck + (size_t)b * CAP;
        for (int i = t; i < cnt; i += 256) {
            unsigned u = bp[i];
            int ld = (int)((u >> 16) & (BUCK_W - 1));
            int slot = atomicAdd(&curS[ld], 1);           // LDS atomic
            colidx[slot] = (unsigned short)(u & 0xffffu);
        }
        return;
    }

    int gbid = (int)blockIdx.x - nbuck;
    int wave = t >> 6, lane = t & 63;
    int mbase = gbid * 64 + wave * 16;
    int arow  = mbase + (lane & 15);
    if (arow >= N) arow = N - 1;             // clamped duplicate reads
    int kgrp  = lane >> 4;                   // 0..3

    // A-frag: lane holds X[arow][kt*32 + kgrp*8 .. +8], converted to fp16
    f16x8 afrag[4];
#pragma unroll
    for (int kt = 0; kt < 4; ++kt) {
        const float* xp = X + (size_t)arow * D + kt * 32 + kgrp * 8;
        float4 a0 = *(const float4*)xp;
        float4 a1 = *(const float4*)(xp + 4);
        f16x8 af;
        af[0] = (_Float16)a0.x; af[1] = (_Float16)a0.y;
        af[2] = (_Float16)a0.z; af[3] = (_Float16)a0.w;
        af[4] = (_Float16)a1.x; af[5] = (_Float16)a1.y;
        af[6] = (_Float16)a1.z; af[7] = (_Float16)a1.w;
        afrag[kt] = af;
    }
    f32x4 acc[8];
#pragma unroll
    for (int nt = 0; nt < 8; ++nt) acc[nt] = (f32x4){0.f, 0.f, 0.f, 0.f};
#pragma unroll
    for (int kt = 0; kt < 4; ++kt) {
#pragma unroll
        for (int nt = 0; nt < 8; ++nt) {
            uint4 u = *(const uint4*)(WB + (((kt * 8 + nt) * 64 + lane) * 8));
            f16x8 bfrag = __builtin_bit_cast(f16x8, u);
            acc[nt] = __builtin_amdgcn_mfma_f32_16x16x32_f16(afrag[kt], bfrag, acc[nt], 0, 0, 0);
        }
    }
    // C/D: col = lane&15, row = kgrp*4 + reg   [m89-verified, dtype-indep]
    int r0 = mbase + kgrp * 4;
#pragma unroll
    for (int r = 0; r < 4; ++r) {
        int row = r0 + r;
        if (row < N) {
            float dv = dinv[row];
#pragma unroll
            for (int nt = 0; nt < 8; ++nt)
                Gh[(size_t)row * D + nt * 16 + (lane & 15)] = (_Float16)(dv * acc[nt][r]);
        }
    }
}

// --- agg1: H''_i = dinv_i * relu(dinv_i*(sum_e G'_s + G'_i) + b1), fp16 -----
// 64-lane wave per node; padded CSR -> branchless 8-deep gather bursts.
__global__ __launch_bounds__(256) void agg1_kernel(const unsigned* __restrict__ Gh,
                                                   const int* __restrict__ rowstart,
                                                   const unsigned short* __restrict__ colidx,
                                                   const float* __restrict__ dinv,
                                                   const float* __restrict__ b1,
                                                   unsigned* __restrict__ Hh,
                                                   int N, int chunk) {
    int gid  = blockIdx.x * 4 + (threadIdx.x >> 6);
    unsigned lane = threadIdx.x & 63;
    int i0 = gid * chunk, i1 = min(i0 + chunk, N);
    float bx = b1[2 * lane], by = b1[2 * lane + 1];
    for (int i = i0; i < i1; ++i) {
        float di = dinv[i];
        float2 acc = h2f(Gh[((unsigned)i << 6) + lane]);    // self term
        int e0 = rowstart[i], e1 = rowstart[i + 1];         // both mult of 8
        for (int e = e0; e < e1; e += 8) {
            u16x8 cc = *(const u16x8*)(colidx + e);         // 16B, aligned
            unsigned u[8];
#pragma unroll
            for (int j = 0; j < 8; ++j)
                u[j] = Gh[((unsigned)cc[j] << 6) + lane];
#pragma unroll
            for (int j = 0; j < 8; ++j) {
                float2 v = h2f(u[j]);
                acc.x += v.x;
                acc.y += v.y;
            }
        }
        float hx = fmaxf(fmaf(di, acc.x, bx), 0.f) * di;    // H'' = dinv*relu
        float hy = fmaxf(fmaf(di, acc.y, by), 0.f) * di;
        Hh[((unsigned)i << 6) + lane] = f2h(hx, hy);
    }
}

// --- agg2 + pool: pool[batch_i] += dinv_i*(sum_e H''_s + H''_i) -------------
__global__ __launch_bounds__(256) void agg2_pool_kernel(const unsigned* __restrict__ Hh,
                                                        const int* __restrict__ rowstart,
                                                        const unsigned short* __restrict__ colidx,
                                                        const float* __restrict__ dinv,
                                                        const int* __restrict__ batch,
                                                        float* __restrict__ pool,
                                                        int N, int chunk) {
    int gid  = blockIdx.x * 4 + (threadIdx.x >> 6);
    unsigned lane = threadIdx.x & 63;
    int i0 = gid * chunk, i1 = min(i0 + chunk, N);
    if (i0 >= N) return;

    float2 pa = make_float2(0.f, 0.f);
    int cur = min(max(batch[i0], 0), NGRAPH - 1);
    for (int i = i0; i < i1; ++i) {
        float di = dinv[i];
        float2 a = h2f(Hh[((unsigned)i << 6) + lane]);      // self term
        int e0 = rowstart[i], e1 = rowstart[i + 1];
        for (int e = e0; e < e1; e += 8) {
            u16x8 cc = *(const u16x8*)(colidx + e);
            unsigned u[8];
#pragma unroll
            for (int j = 0; j < 8; ++j)
                u[j] = Hh[((unsigned)cc[j] << 6) + lane];
#pragma unroll
            for (int j = 0; j < 8; ++j) {
                float2 v = h2f(u[j]);
                a.x += v.x;
                a.y += v.y;
            }
        }
        int b = min(max(batch[i], 0), NGRAPH - 1);
        if (b != cur) {                                     // uniform per wave
            atomicAdd(&pool[(size_t)cur * D + 2 * lane], pa.x);
            atomicAdd(&pool[(size_t)cur * D + 2 * lane + 1], pa.y);
            pa = make_float2(0.f, 0.f);
            cur = b;
        }
        pa.x = fmaf(di, a.x, pa.x);
        pa.y = fmaf(di, a.y, pa.y);
    }
    atomicAdd(&pool[(size_t)cur * D + 2 * lane], pa.x);
    atomicAdd(&pool[(size_t)cur * D + 2 * lane + 1], pa.y);
}

// --- Final tiny GEMM: out[g][o] = (pool[g]/cnt_g) . W2[:,o] + b2[o] ---------
__device__ __forceinline__ int lbound(const int* __restrict__ a, int n, int v) {
    int lo = 0, hi = n;
    while (lo < hi) {
        int m = (lo + hi) >> 1;
        if (a[m] < v) lo = m + 1; else hi = m;
    }
    return lo;
}

__global__ void final_gemm_kernel(const float* __restrict__ pool,
                                  const int* __restrict__ batch,
                                  const float* __restrict__ W2,
                                  const float* __restrict__ b2,
                                  float* __restrict__ out, int N) {
    int g = blockIdx.x, o = threadIdx.x;
    int s = lbound(batch, N, g);
    int e = lbound(batch, N, g + 1);
    float inv_cnt = 1.0f / fmaxf((float)(e - s), 1.0f);
    float acc = 0.f;
#pragma unroll 4
    for (int k = 0; k < D; ++k)
        acc = fmaf(pool[g * D + k], W2[k * D + o], acc);
    out[g * D + o] = acc * inv_cnt + b2[o];
}

// ---------------------------------------------------------------------------

extern "C" void kernel_launch(void* const* d_in, const int* in_sizes, int n_in,
                              void* d_out, int out_size, void* d_ws, size_t ws_size,
                              hipStream_t stream) {
    const float* x     = (const float*)d_in[0];
    const int*   ei    = (const int*)  d_in[1];
    const int*   batch = (const int*)  d_in[2];
    const float* W1    = (const float*)d_in[3];
    const float* b1    = (const float*)d_in[4];
    const float* W2    = (const float*)d_in[5];
    const float* b2    = (const float*)d_in[6];
    float* out = (float*)d_out;

    const int N = in_sizes[0] / D;
    const int E = in_sizes[1] / 2;
    const int nbuck = (N + BUCK_W - 1) >> BUCK_SH;      // <=256 for N<=65536
    const int CAP   = (E / (nbuck > 0 ? nbuck : 1)) * 2 + 1024;

    // workspace carve-up (256B aligned); bcnt+pool+ticket -> single memset
    char* ws = (char*)d_ws;
    size_t off = 0;
    auto carve = [&](size_t bytes) {
        size_t o = off;
        off = (off + bytes + 255) & ~(size_t)255;
        return o;
    };
    size_t o_bcnt     = carve((size_t)MAXBUCK * 4);
    size_t o_pool     = carve((size_t)NGRAPH * D * 4);
    size_t o_ticket   = carve((size_t)256);
    size_t zspan      = off;                       // memset [0, zspan)
    size_t o_rowstart = carve((size_t)(N + 1) * 4);
    size_t o_deg      = carve((size_t)N * 4);
    size_t o_dinv     = carve((size_t)N * 4);
    size_t o_padsum   = carve((size_t)MAXBUCK * 4);
    size_t o_bbase    = carve((size_t)MAXBUCK * 4);
    size_t o_colidx   = carve(((size_t)E + 7 * (size_t)N + 64) * 2);  // padded
    size_t o_buck     = carve((size_t)nbuck * CAP * 4);
    size_t o_wb       = carve((size_t)D * D * 2);        // fp16 W1 (MFMA B)
    size_t o_gh       = carve((size_t)(N + 1) * D * 2);  // fp16 G' (+zero row)
    size_t o_hh       = carve((size_t)(N + 1) * D * 2);  // fp16 H'' (+zero row)
    size_t need = off;

    if (ws_size < need) {
        zero_out_kernel<<<(out_size + 255) / 256, 256, 0, stream>>>(out, out_size);
        return;
    }

    int*            bcnt     = (int*)           (ws + o_bcnt);
    float*          pool     = (float*)         (ws + o_pool);
    int*            ticket   = (int*)           (ws + o_ticket);
    int*            rowstart = (int*)           (ws + o_rowstart);
    int*            deg      = (int*)           (ws + o_deg);
    float*          dinv     = (float*)         (ws + o_dinv);
    int*            padsum   = (int*)           (ws + o_padsum);
    int*            bbase    = (int*)           (ws + o_bbase);
    unsigned short* colidx   = (unsigned short*)(ws + o_colidx);
    unsigned*       buck     = (unsigned*)      (ws + o_buck);
    _Float16*       WB       = (_Float16*)      (ws + o_wb);
    _Float16*       Gh       = (_Float16*)      (ws + o_gh);
    _Float16*       Hh       = (_Float16*)      (ws + o_hh);

    hipMemsetAsync(ws, 0, zspan, stream);          // bcnt + pool + ticket

    int ebs = (E + 1023) / 1024;                   // scatter: 4 edges/thread
    int gb  = (N + 63) / 64;

    pack_scatter_kernel<<<9 + ebs, 256, 0, stream>>>(W1, WB, ei, bcnt, buck,
                                                     (unsigned*)Gh, (unsigned*)Hh,
                                                     N, E, CAP);
    bucket_deg_kernel<<<nbuck, 256, 0, stream>>>(buck, bcnt, deg, dinv, padsum,
                                                 bbase, rowstart, ticket,
                                                 N, CAP, nbuck);
    gemm_fill_kernel<<<nbuck + gb, 256, 0, stream>>>(x, WB, dinv, Gh, buck, bcnt,
                                                     deg, bbase, rowstart, colidx,
                                                     N, CAP, nbuck);

    int groups = AGG_BLOCKS * 4;
    int chunk  = (N + groups - 1) / groups;
    agg1_kernel<<<AGG_BLOCKS, 256, 0, stream>>>((const unsigned*)Gh, rowstart, colidx,
                                                dinv, b1, (unsigned*)Hh, N, chunk);
    agg2_pool_kernel<<<AGG_BLOCKS, 256, 0, stream>>>((const unsigned*)Hh, rowstart, colidx,
                                                     dinv, batch, pool, N, chunk);
    final_gemm_kernel<<<NGRAPH, D, 0, stream>>>(pool, batch, W2, b2, out, N);
}